// Round 14
// baseline (96.237 us; speedup 1.0000x reference)
//
#include <hip/hip_runtime.h>

#define ALPHA 0.2f
#define NN 4096
#define IN_DIM 128
#define REPR 64
#define HEADS 8
#define NCOLP 768   // P stride: 512 num + 8 den @512..519 + pad (never stored/read)
#define KSPLIT 8
#define PLANE_ELEMS (NN * NCOLP)

typedef _Float16 f16;
typedef _Float16 f16x8 __attribute__((ext_vector_type(8)));
typedef float f32x4 __attribute__((ext_vector_type(4)));

union F16x8U { f16 e[8]; f16x8 v; };

// ws layout (bytes) — ws_size = 256 MiB
#define WS_P   0u            // 8*4096*768*2 = 50331648
#define WS_HID 50331648u     // 8388608
#define WS_F2  58720256u     // 131072
#define WS_MX  58851328u     // 4096
#define WS_A16 58855424u     // 4096*4096*2 = 33554432
#define WS_MT  92409856u     // 768*4096*2 = 6291456
#define WS_END 98701312u

// ---------- k_pre: fused (hidden+f2 | adjacency cvt) ----------
// blocks 0..1023: hidden[i,j,l] = sum_k node[j,k]*W[i,k,l] + fused f2
// blocks 1024..9215: A fp32 -> f16 (0/1 exact), streaming
__global__ __launch_bounds__(256) void k_pre(const float* __restrict__ node,
                                             const float* __restrict__ W,
                                             const float* __restrict__ sa,
                                             const float* __restrict__ adj,
                                             float* __restrict__ hidden,
                                             float* __restrict__ f2,
                                             f16* __restrict__ A16) {
  __shared__ float nl[32][137];
  __shared__ __align__(16) float wl[128][64];
  const int t = threadIdx.x;

  if (blockIdx.x >= 1024) {
    // ---- acvt branch ----
    const size_t idx = (size_t)(blockIdx.x - 1024) * 256 + t;
    const float4* a4 = (const float4*)adj;
    float4 u = a4[idx*2], w = a4[idx*2+1];
    F16x8U o;
    o.e[0]=(f16)u.x; o.e[1]=(f16)u.y; o.e[2]=(f16)u.z; o.e[3]=(f16)u.w;
    o.e[4]=(f16)w.x; o.e[5]=(f16)w.y; o.e[6]=(f16)w.z; o.e[7]=(f16)w.w;
    *(f16x8*)&A16[idx*8] = o.v;
    return;
  }

  // ---- hidden branch ----
  const int i = blockIdx.x >> 7;            // 0..7
  const int jb = (blockIdx.x & 127) * 32;   // 0..4064
  const float4* gn = (const float4*)(node + (size_t)jb * IN_DIM);
  #pragma unroll
  for (int q = 0; q < 4; ++q) {
    int i4 = q * 256 + t;
    int r = i4 >> 5, c4 = i4 & 31;
    float4 v = gn[i4];
    nl[r][c4*4+0] = v.x; nl[r][c4*4+1] = v.y; nl[r][c4*4+2] = v.z; nl[r][c4*4+3] = v.w;
  }
  const float4* gw = (const float4*)(W + (size_t)i * IN_DIM * REPR);
  #pragma unroll
  for (int q = 0; q < 8; ++q) {
    int i4 = q * 256 + t;
    int r = i4 >> 4, c4 = i4 & 15;
    *(float4*)&wl[r][c4*4] = gw[i4];
  }
  __syncthreads();
  const int tx = t & 15, ty = t >> 4;
  float acc0[4] = {0,0,0,0}, acc1[4] = {0,0,0,0};
  #pragma unroll 4
  for (int k = 0; k < 128; ++k) {
    float a0 = nl[2*ty][k], a1 = nl[2*ty+1][k];
    float4 b = *(const float4*)&wl[k][4*tx];
    acc0[0] += a0*b.x; acc0[1] += a0*b.y; acc0[2] += a0*b.z; acc0[3] += a0*b.w;
    acc1[0] += a1*b.x; acc1[1] += a1*b.y; acc1[2] += a1*b.z; acc1[3] += a1*b.w;
  }
  float* o0 = hidden + ((size_t)i*NN + jb + 2*ty) * REPR + 4*tx;
  *(float4*)o0 = make_float4(acc0[0],acc0[1],acc0[2],acc0[3]);
  *(float4*)(o0 + REPR) = make_float4(acc1[0],acc1[1],acc1[2],acc1[3]);

  float4 ad = *(const float4*)(sa + i * 2 * REPR + REPR + 4*tx);
  float s0 = 0.f, s1 = 0.f, x;
  x = acc0[0]; s0 += (x > 0.f ? x : ALPHA*x) * ad.x;
  x = acc0[1]; s0 += (x > 0.f ? x : ALPHA*x) * ad.y;
  x = acc0[2]; s0 += (x > 0.f ? x : ALPHA*x) * ad.z;
  x = acc0[3]; s0 += (x > 0.f ? x : ALPHA*x) * ad.w;
  x = acc1[0]; s1 += (x > 0.f ? x : ALPHA*x) * ad.x;
  x = acc1[1]; s1 += (x > 0.f ? x : ALPHA*x) * ad.y;
  x = acc1[2]; s1 += (x > 0.f ? x : ALPHA*x) * ad.z;
  x = acc1[3]; s1 += (x > 0.f ? x : ALPHA*x) * ad.w;
  #pragma unroll
  for (int d = 8; d > 0; d >>= 1) {
    s0 += __shfl_down(s0, d, 16);
    s1 += __shfl_down(s1, d, 16);
  }
  if (tx == 0) {
    f2[i*NN + jb + 2*ty]     = s0;
    f2[i*NN + jb + 2*ty + 1] = s1;
  }
}

// ---------- k3: per-head max of f2 ----------
__global__ __launch_bounds__(256) void k_max(const float* __restrict__ f2,
                                             float* __restrict__ mx) {
  const int i = blockIdx.x, t = threadIdx.x;
  __shared__ float red[256];
  float m = -1e30f;
  #pragma unroll
  for (int q = 0; q < 16; ++q) m = fmaxf(m, f2[i*NN + q*256 + t]);
  red[t] = m; __syncthreads();
  for (int s = 128; s > 0; s >>= 1) {
    if (t < s) red[t] = fmaxf(red[t], red[t + s]);
    __syncthreads();
  }
  if (t == 0) mx[i] = red[0];
}

// ---------- k4 fused: numerator rows (y<128) + denominator rows (y==128) ----------
__global__ __launch_bounds__(256) void k_mt(const float* __restrict__ hidden,
                                            const float* __restrict__ f2,
                                            const float* __restrict__ mx,
                                            f16* __restrict__ MT) {
  const int i = blockIdx.x;
  const float m = mx[i];
  if (blockIdx.y < 128) {
    const int l = threadIdx.x & 63, q = threadIdx.x >> 6;
    const int k0 = blockIdx.y * 32 + q * 8;
    float g[8];
    #pragma unroll
    for (int kk = 0; kk < 8; ++kk) g[kk] = __expf(f2[i*NN + k0 + kk] - m);
    F16x8U u;
    #pragma unroll
    for (int kk = 0; kk < 8; ++kk) {
      float h = hidden[((size_t)i*NN + k0 + kk) * REPR + l];
      u.e[kk] = (f16)(g[kk] * h);
    }
    *(f16x8*)&MT[(size_t)(i*REPR + l) * NN + k0] = u.v;
  } else {
    #pragma unroll
    for (int q = 0; q < 2; ++q) {
      const int k0 = (threadIdx.x * 2 + q) * 8;
      F16x8U u;
      #pragma unroll
      for (int kk = 0; kk < 8; ++kk) u.e[kk] = (f16)__expf(f2[i*NN + k0 + kk] - m);
      *(f16x8*)&MT[(size_t)(512 + i) * NN + k0] = u.v;
    }
  }
}

// ---------- k6: 256x256-tile GEMM, 8-phase schedule (T3+T4+T5 port of m201) ----------
// Layout/addressing identical to R13 (zero-conflict proven). Per K-tile: 4
// phases of {2 staging gload_lds (t+1, spread) ; 8/4 ds_read_b128 ; s_barrier ;
// lgkmcnt(0)+sched_barrier(0) ; setprio(1) ; 16 MFMA ; setprio(0) ; s_barrier}.
// Tile boundary: vmcnt(0)+barrier (t+1's loads issued >=4 phases earlier).
__global__ __launch_bounds__(512) void k_gemm(const f16* __restrict__ A16,
                                              const f16* __restrict__ MT,
                                              f16* __restrict__ P) {
  __shared__ __align__(16) f16 smA[2][256*64];   // 2 x 32 KB
  __shared__ __align__(16) f16 smB[2][256*64];   // 2 x 32 KB
  const int t = threadIdx.x;
  const int lane = t & 63, wid = t >> 6;         // wid 0..7

  const int lin = blockIdx.x;                    // 0..383
  const int xcd = lin & 7, idx = lin >> 3;       // idx 0..47
  const int jt  = xcd + 8 * (idx / 24);          // 0..15
  const int r   = idx % 24;
  const int ct  = r % 3;                         // 0..2
  const int zt  = r / 3;                         // 0..7

  const int j0 = jt * 256;
  const int c0 = ct * 256;
  const int kz = zt * 512;                       // 8 K-tiles of 64
  const int NK = 8;

  const char* Ab = (const char*)A16;
  const char* Bb = (const char*)MT;
  size_t ga[4], gb[4]; int cb[4];
  #pragma unroll
  for (int q = 0; q < 4; ++q) {
    int ci = q*512 + t;
    int m = ci >> 3, s = ci & 7;
    int c = s ^ (m & 7);                         // inverse-swizzled source chunk
    ga[q] = ((size_t)(j0 + m) * NN + kz) * 2 + (size_t)c * 16;
    gb[q] = ((size_t)(c0 + m) * NN + kz) * 2 + (size_t)c * 16;
    cb[q] = (q*512 + wid*64) * 16;               // wave-uniform LDS dest base
  }

  const int frow = lane & 15, kg = lane >> 4;
  const int wr = wid >> 2, wc = wid & 3;         // 2 x 4 wave grid
  int arow[8], brow[4], soff[2];
  #pragma unroll
  for (int mi = 0; mi < 8; ++mi) arow[mi] = (wr*128 + mi*16 + frow) * 128; // bytes
  #pragma unroll
  for (int ni = 0; ni < 4; ++ni) brow[ni] = (wc*64 + ni*16 + frow) * 128;  // bytes
  #pragma unroll
  for (int kk = 0; kk < 2; ++kk) soff[kk] = ((kk*4 + kg) ^ (frow & 7)) * 16;

#define SG_A(BUF, KT, Q) \
    __builtin_amdgcn_global_load_lds( \
      (const __attribute__((address_space(1))) void*)(Ab + ga[Q] + (size_t)(KT)*128), \
      (__attribute__((address_space(3))) void*)((char*)smA[BUF] + cb[Q]), 16, 0, 0)
#define SG_B(BUF, KT, Q) \
    __builtin_amdgcn_global_load_lds( \
      (const __attribute__((address_space(1))) void*)(Bb + gb[Q] + (size_t)(KT)*128), \
      (__attribute__((address_space(3))) void*)((char*)smB[BUF] + cb[Q]), 16, 0, 0)

  f32x4 acc[8][4] = {};
  f16x8 fa[4], fb[4];

// one phase: staging code, optional b-read, a-reads for MIBASE..MIBASE+3 at KK
#define PHASE(STAGE_CODE, READ_B, KK, MIBASE) do { \
    STAGE_CODE; \
    if (READ_B) { \
      _Pragma("unroll") \
      for (int ni = 0; ni < 4; ++ni) \
        fb[ni] = *(const f16x8*)(bufB + brow[ni] + soff[KK]); \
    } \
    _Pragma("unroll") \
    for (int mi = 0; mi < 4; ++mi) \
      fa[mi] = *(const f16x8*)(bufA + arow[(MIBASE)+mi] + soff[KK]); \
    __builtin_amdgcn_s_barrier(); \
    asm volatile("s_waitcnt lgkmcnt(0)" ::: "memory"); \
    __builtin_amdgcn_sched_barrier(0); \
    __builtin_amdgcn_s_setprio(1); \
    _Pragma("unroll") \
    for (int mi = 0; mi < 4; ++mi) \
      _Pragma("unroll") \
      for (int ni = 0; ni < 4; ++ni) \
        acc[(MIBASE)+mi][ni] = __builtin_amdgcn_mfma_f32_16x16x32_f16(fa[mi], fb[ni], acc[(MIBASE)+mi][ni], 0, 0, 0); \
    __builtin_amdgcn_s_setprio(0); \
    __builtin_amdgcn_s_barrier(); \
  } while (0)

  // prologue: tile 0 staged, drained once
  #pragma unroll
  for (int q = 0; q < 4; ++q) { SG_A(0, 0, q); SG_B(0, 0, q); }
  asm volatile("s_waitcnt vmcnt(0)" ::: "memory");
  __builtin_amdgcn_s_barrier();

  #pragma unroll 1
  for (int kt = 0; kt < NK; ++kt) {
    const int cur = kt & 1, nxt = cur ^ 1;
    const char* bufA = (const char*)smA[cur];
    const char* bufB = (const char*)smB[cur];
    const int pf = (kt + 1 < NK);
    const int kn = pf ? kt + 1 : kt;            // clamped (predicated off)
    PHASE({ if (pf) { SG_A(nxt, kn, 0); SG_A(nxt, kn, 1); } }, 1, 0, 0);
    PHASE({ if (pf) { SG_A(nxt, kn, 2); SG_A(nxt, kn, 3); } }, 0, 0, 4);
    PHASE({ if (pf) { SG_B(nxt, kn, 0); SG_B(nxt, kn, 1); } }, 1, 1, 0);
    PHASE({ if (pf) { SG_B(nxt, kn, 2); SG_B(nxt, kn, 3); } }, 0, 1, 4);
    asm volatile("s_waitcnt vmcnt(0)" ::: "memory");   // t+1 landed (issued 4 phases ago)
    __builtin_amdgcn_s_barrier();
  }

  f16* Pz = P + (size_t)zt * PLANE_ELEMS;
  if (ct != 2) {
    #pragma unroll
    for (int mi = 0; mi < 8; ++mi) {
      const int orow = j0 + wr*128 + mi*16 + kg*4;
      #pragma unroll
      for (int ni = 0; ni < 4; ++ni) {
        const int ocol = c0 + wc*64 + ni*16 + frow;
        #pragma unroll
        for (int r4 = 0; r4 < 4; ++r4)
          Pz[(size_t)(orow + r4) * NCOLP + ocol] = (f16)acc[mi][ni][r4];
      }
    }
  } else if (wc == 0 && frow < 8) {
    // pad-store skip: only den columns 512..519 (ni==0) are live
    #pragma unroll
    for (int mi = 0; mi < 8; ++mi) {
      const int orow = j0 + wr*128 + mi*16 + kg*4;
      const int ocol = 512 + frow;
      #pragma unroll
      for (int r4 = 0; r4 < 4; ++r4)
        Pz[(size_t)(orow + r4) * NCOLP + ocol] = (f16)acc[mi][0][r4];
    }
  }
#undef PHASE
#undef SG_A
#undef SG_B
}

// ---------- k7: out[j, i*64+l] = num/den over 8 split-K planes ----------
__global__ __launch_bounds__(256) void k_div(const f16* __restrict__ P,
                                             float* __restrict__ out) {
  const int gid = blockIdx.x * 256 + threadIdx.x;   // 2,097,152
  const int j = gid >> 9, c = gid & 511, i = c >> 6;
  const size_t rc = (size_t)j*NCOLP + c;
  const size_t rd = (size_t)j*NCOLP + 512 + i;
  float num = 0.f, den = 0.f;
  #pragma unroll
  for (int z = 0; z < KSPLIT; ++z) {
    const f16* Pz = P + (size_t)z * PLANE_ELEMS;
    num += (float)Pz[rc];
    den += (float)Pz[rd];
  }
  out[gid] = num / den;
}

extern "C" void kernel_launch(void* const* d_in, const int* in_sizes, int n_in,
                              void* d_out, int out_size, void* d_ws, size_t ws_size,
                              hipStream_t stream) {
  const float* node = (const float*)d_in[0];
  const float* adj  = (const float*)d_in[1];
  const float* W    = (const float*)d_in[2];
  const float* sa   = (const float*)d_in[3];
  float* out = (float*)d_out;
  char* ws = (char*)d_ws;
  if (ws_size < (size_t)WS_END) return;

  float* hidden = (float*)(ws + WS_HID);
  float* f2     = (float*)(ws + WS_F2);
  float* mx     = (float*)(ws + WS_MX);
  f16*   A16    = (f16*)(ws + WS_A16);
  f16*   MT     = (f16*)(ws + WS_MT);
  f16*   P      = (f16*)(ws + WS_P);

  k_pre   <<<dim3(9216),      256, 0, stream>>>(node, W, sa, adj, hidden, f2, A16);
  k_max   <<<dim3(8),         256, 0, stream>>>(f2, mx);
  k_mt    <<<dim3(8, 129),    256, 0, stream>>>(hidden, f2, mx, MT);
  k_gemm  <<<dim3(384),       512, 0, stream>>>(A16, MT, P);
  k_div   <<<dim3(8192),      256, 0, stream>>>(P, out);
}

// Round 15
// 71.178 us; speedup vs baseline: 1.3521x; 1.3521x over previous
//
#include <hip/hip_runtime.h>

#define ALPHA 0.2f
#define NN 4096
#define IN_DIM 128
#define REPR 64
#define HEADS 8
#define NCOLP 640   // P stride: 512 num + 8 den @512..519 + 120 pad (not stored)
#define KSPLIT 8
#define PLANE_ELEMS (NN * NCOLP)

typedef _Float16 f16;
typedef _Float16 f16x8 __attribute__((ext_vector_type(8)));
typedef float f32x4 __attribute__((ext_vector_type(4)));

union F16x8U { f16 e[8]; f16x8 v; };

// ws layout (bytes) — ws_size = 256 MiB
#define WS_P   0u            // 8*4096*640*2 = 41943040
#define WS_HID 41943040u     // 8388608
#define WS_F2  50331648u     // 131072
#define WS_MX  50462720u     // 4096
#define WS_A16 50466816u     // 4096*4096*2 = 33554432
#define WS_MT  84021248u     // 768*4096*2 = 6291456 (rows 520..767 unused)
#define WS_END 90312704u

// ---------- k_pre: fused (hidden+f2 | adjacency cvt) ----------
__global__ __launch_bounds__(256) void k_pre(const float* __restrict__ node,
                                             const float* __restrict__ W,
                                             const float* __restrict__ sa,
                                             const float* __restrict__ adj,
                                             float* __restrict__ hidden,
                                             float* __restrict__ f2,
                                             f16* __restrict__ A16) {
  __shared__ float nl[32][137];
  __shared__ __align__(16) float wl[128][64];
  const int t = threadIdx.x;

  if (blockIdx.x >= 1024) {
    const size_t idx = (size_t)(blockIdx.x - 1024) * 256 + t;
    const float4* a4 = (const float4*)adj;
    float4 u = a4[idx*2], w = a4[idx*2+1];
    F16x8U o;
    o.e[0]=(f16)u.x; o.e[1]=(f16)u.y; o.e[2]=(f16)u.z; o.e[3]=(f16)u.w;
    o.e[4]=(f16)w.x; o.e[5]=(f16)w.y; o.e[6]=(f16)w.z; o.e[7]=(f16)w.w;
    *(f16x8*)&A16[idx*8] = o.v;
    return;
  }

  const int i = blockIdx.x >> 7;
  const int jb = (blockIdx.x & 127) * 32;
  const float4* gn = (const float4*)(node + (size_t)jb * IN_DIM);
  #pragma unroll
  for (int q = 0; q < 4; ++q) {
    int i4 = q * 256 + t;
    int r = i4 >> 5, c4 = i4 & 31;
    float4 v = gn[i4];
    nl[r][c4*4+0] = v.x; nl[r][c4*4+1] = v.y; nl[r][c4*4+2] = v.z; nl[r][c4*4+3] = v.w;
  }
  const float4* gw = (const float4*)(W + (size_t)i * IN_DIM * REPR);
  #pragma unroll
  for (int q = 0; q < 8; ++q) {
    int i4 = q * 256 + t;
    int r = i4 >> 4, c4 = i4 & 15;
    *(float4*)&wl[r][c4*4] = gw[i4];
  }
  __syncthreads();
  const int tx = t & 15, ty = t >> 4;
  float acc0[4] = {0,0,0,0}, acc1[4] = {0,0,0,0};
  #pragma unroll 4
  for (int k = 0; k < 128; ++k) {
    float a0 = nl[2*ty][k], a1 = nl[2*ty+1][k];
    float4 b = *(const float4*)&wl[k][4*tx];
    acc0[0] += a0*b.x; acc0[1] += a0*b.y; acc0[2] += a0*b.z; acc0[3] += a0*b.w;
    acc1[0] += a1*b.x; acc1[1] += a1*b.y; acc1[2] += a1*b.z; acc1[3] += a1*b.w;
  }
  float* o0 = hidden + ((size_t)i*NN + jb + 2*ty) * REPR + 4*tx;
  *(float4*)o0 = make_float4(acc0[0],acc0[1],acc0[2],acc0[3]);
  *(float4*)(o0 + REPR) = make_float4(acc1[0],acc1[1],acc1[2],acc1[3]);

  float4 ad = *(const float4*)(sa + i * 2 * REPR + REPR + 4*tx);
  float s0 = 0.f, s1 = 0.f, x;
  x = acc0[0]; s0 += (x > 0.f ? x : ALPHA*x) * ad.x;
  x = acc0[1]; s0 += (x > 0.f ? x : ALPHA*x) * ad.y;
  x = acc0[2]; s0 += (x > 0.f ? x : ALPHA*x) * ad.z;
  x = acc0[3]; s0 += (x > 0.f ? x : ALPHA*x) * ad.w;
  x = acc1[0]; s1 += (x > 0.f ? x : ALPHA*x) * ad.x;
  x = acc1[1]; s1 += (x > 0.f ? x : ALPHA*x) * ad.y;
  x = acc1[2]; s1 += (x > 0.f ? x : ALPHA*x) * ad.z;
  x = acc1[3]; s1 += (x > 0.f ? x : ALPHA*x) * ad.w;
  #pragma unroll
  for (int d = 8; d > 0; d >>= 1) {
    s0 += __shfl_down(s0, d, 16);
    s1 += __shfl_down(s1, d, 16);
  }
  if (tx == 0) {
    f2[i*NN + jb + 2*ty]     = s0;
    f2[i*NN + jb + 2*ty + 1] = s1;
  }
}

// ---------- k3: per-head max of f2 ----------
__global__ __launch_bounds__(256) void k_max(const float* __restrict__ f2,
                                             float* __restrict__ mx) {
  const int i = blockIdx.x, t = threadIdx.x;
  __shared__ float red[256];
  float m = -1e30f;
  #pragma unroll
  for (int q = 0; q < 16; ++q) m = fmaxf(m, f2[i*NN + q*256 + t]);
  red[t] = m; __syncthreads();
  for (int s = 128; s > 0; s >>= 1) {
    if (t < s) red[t] = fmaxf(red[t], red[t + s]);
    __syncthreads();
  }
  if (t == 0) mx[i] = red[0];
}

// ---------- k4 fused: numerator rows (y<128) + denominator rows (y==128) ----------
__global__ __launch_bounds__(256) void k_mt(const float* __restrict__ hidden,
                                            const float* __restrict__ f2,
                                            const float* __restrict__ mx,
                                            f16* __restrict__ MT) {
  const int i = blockIdx.x;
  const float m = mx[i];
  if (blockIdx.y < 128) {
    const int l = threadIdx.x & 63, q = threadIdx.x >> 6;
    const int k0 = blockIdx.y * 32 + q * 8;
    float g[8];
    #pragma unroll
    for (int kk = 0; kk < 8; ++kk) g[kk] = __expf(f2[i*NN + k0 + kk] - m);
    F16x8U u;
    #pragma unroll
    for (int kk = 0; kk < 8; ++kk) {
      float h = hidden[((size_t)i*NN + k0 + kk) * REPR + l];
      u.e[kk] = (f16)(g[kk] * h);
    }
    *(f16x8*)&MT[(size_t)(i*REPR + l) * NN + k0] = u.v;
  } else {
    #pragma unroll
    for (int q = 0; q < 2; ++q) {
      const int k0 = (threadIdx.x * 2 + q) * 8;
      F16x8U u;
      #pragma unroll
      for (int kk = 0; kk < 8; ++kk) u.e[kk] = (f16)__expf(f2[i*NN + k0 + kk] - m);
      *(f16x8*)&MT[(size_t)(512 + i) * NN + k0] = u.v;
    }
  }
}

// ---------- k6: 256x320-tile GEMM, counted-vmcnt dbuf, grid EXACTLY 256 ----------
// P[z][j][c] = sum_{k in split z} A16[j,k] * MT[c,k].
// BM=256, BN=320 (2 ct tiles cover all 520 useful cols), BK=64, 8 waves
// (2Mx4N), wave-tile 128x80 (acc[8][5]). LDS 144KB dbuf (1 block/CU).
// grid 256 = 16jt x 2ct x 8zt -> ONE perfectly balanced round (R13 ran 384
// blocks = 2 rounds, 2nd half-empty). Loop: STAGE(t+1) -> vmcnt(9) ->
// barrier -> compute -> barrier; vmcnt(0) only on the last tile.
// MT rows 520..639 are stale poison (finite f16) -> stores predicated ocol<520.
__global__ __launch_bounds__(512) void k_gemm(const f16* __restrict__ A16,
                                              const f16* __restrict__ MT,
                                              f16* __restrict__ P) {
  __shared__ __align__(16) f16 smA[2][256*64];   // 2 x 32 KB
  __shared__ __align__(16) f16 smB[2][320*64];   // 2 x 40 KB
  const int t = threadIdx.x;
  const int lane = t & 63, wid = t >> 6;         // wid 0..7

  const int lin = blockIdx.x;                    // 0..255
  const int xcd = lin & 7, idx = lin >> 3;       // idx 0..31
  const int jt  = xcd + 8 * (idx / 16);          // 0..15
  const int r   = idx % 16;
  const int ct  = r & 1;                         // 0..1
  const int zt  = r >> 1;                        // 0..7

  const int j0 = jt * 256;
  const int c0 = ct * 320;
  const int kz = zt * 512;                       // 8 K-tiles of 64
  const int NK = 8;

  const char* Ab = (const char*)A16;
  const char* Bb = (const char*)MT;
  size_t ga[4]; int cbA[4];
  #pragma unroll
  for (int q = 0; q < 4; ++q) {                  // A: 2048 chunks, 4/thread
    int ci = q*512 + t;
    int m = ci >> 3, s = ci & 7;
    int c = s ^ (m & 7);
    ga[q]  = ((size_t)(j0 + m) * NN + kz) * 2 + (size_t)c * 16;
    cbA[q] = (q*512 + wid*64) * 16;
  }
  size_t gb[5]; int cbB[5];
  #pragma unroll
  for (int q = 0; q < 5; ++q) {                  // B: 2560 chunks, 5/thread
    int ci = q*512 + t;
    int m = ci >> 3, s = ci & 7;
    int c = s ^ (m & 7);
    gb[q]  = ((size_t)(c0 + m) * NN + kz) * 2 + (size_t)c * 16;
    cbB[q] = (q*512 + wid*64) * 16;
  }

  const int frow = lane & 15, kg = lane >> 4;
  const int wr = wid >> 2, wc = wid & 3;         // 2 x 4 wave grid
  int arow[8], brow[5], soff[2];
  #pragma unroll
  for (int mi = 0; mi < 8; ++mi) arow[mi] = (wr*128 + mi*16 + frow) * 128; // bytes
  #pragma unroll
  for (int ni = 0; ni < 5; ++ni) brow[ni] = (wc*80 + ni*16 + frow) * 128;  // bytes
  #pragma unroll
  for (int kk = 0; kk < 2; ++kk) soff[kk] = ((kk*4 + kg) ^ (frow & 7)) * 16;

#define STAGE(BUF, KT) do { \
    const size_t kb_ = (size_t)(KT) * 128;  /* 64 f16 */ \
    _Pragma("unroll") \
    for (int q = 0; q < 4; ++q) \
      __builtin_amdgcn_global_load_lds( \
        (const __attribute__((address_space(1))) void*)(Ab + ga[q] + kb_), \
        (__attribute__((address_space(3))) void*)((char*)smA[BUF] + cbA[q]), 16, 0, 0); \
    _Pragma("unroll") \
    for (int q = 0; q < 5; ++q) \
      __builtin_amdgcn_global_load_lds( \
        (const __attribute__((address_space(1))) void*)(Bb + gb[q] + kb_), \
        (__attribute__((address_space(3))) void*)((char*)smB[BUF] + cbB[q]), 16, 0, 0); \
  } while (0)

  f32x4 acc[8][5] = {};

  STAGE(0, 0);
  #pragma unroll 1
  for (int kt = 0; kt < NK; ++kt) {
    const int cur = kt & 1;
    if (kt + 1 < NK) {
      STAGE(cur ^ 1, kt + 1);
      asm volatile("s_waitcnt vmcnt(9)" ::: "memory");   // kt landed, kt+1 in flight
    } else {
      asm volatile("s_waitcnt vmcnt(0)" ::: "memory");
    }
    __builtin_amdgcn_s_barrier();
    const char* bufA = (const char*)smA[cur];
    const char* bufB = (const char*)smB[cur];
    #pragma unroll
    for (int kk = 0; kk < 2; ++kk) {
      f16x8 a[8], b[5];
      #pragma unroll
      for (int mi = 0; mi < 8; ++mi)
        a[mi] = *(const f16x8*)(bufA + arow[mi] + soff[kk]);
      #pragma unroll
      for (int ni = 0; ni < 5; ++ni)
        b[ni] = *(const f16x8*)(bufB + brow[ni] + soff[kk]);
      #pragma unroll
      for (int mi = 0; mi < 8; ++mi)
        #pragma unroll
        for (int ni = 0; ni < 5; ++ni)
          acc[mi][ni] = __builtin_amdgcn_mfma_f32_16x16x32_f16(a[mi], b[ni], acc[mi][ni], 0, 0, 0);
    }
    __builtin_amdgcn_s_barrier();
  }

  f16* Pz = P + (size_t)zt * PLANE_ELEMS;
  #pragma unroll
  for (int mi = 0; mi < 8; ++mi) {
    const int orow = j0 + wr*128 + mi*16 + kg*4;
    #pragma unroll
    for (int ni = 0; ni < 5; ++ni) {
      const int ocol = c0 + wc*80 + ni*16 + frow;
      if (ocol < 520) {
        #pragma unroll
        for (int r4 = 0; r4 < 4; ++r4)
          Pz[(size_t)(orow + r4) * NCOLP + ocol] = (f16)acc[mi][ni][r4];
      }
    }
  }
#undef STAGE
}

// ---------- k7: out[j, i*64+l] = num/den over 8 split-K planes ----------
__global__ __launch_bounds__(256) void k_div(const f16* __restrict__ P,
                                             float* __restrict__ out) {
  const int gid = blockIdx.x * 256 + threadIdx.x;   // 2,097,152
  const int j = gid >> 9, c = gid & 511, i = c >> 6;
  const size_t rc = (size_t)j*NCOLP + c;
  const size_t rd = (size_t)j*NCOLP + 512 + i;
  float num = 0.f, den = 0.f;
  #pragma unroll
  for (int z = 0; z < KSPLIT; ++z) {
    const f16* Pz = P + (size_t)z * PLANE_ELEMS;
    num += (float)Pz[rc];
    den += (float)Pz[rd];
  }
  out[gid] = num / den;
}

extern "C" void kernel_launch(void* const* d_in, const int* in_sizes, int n_in,
                              void* d_out, int out_size, void* d_ws, size_t ws_size,
                              hipStream_t stream) {
  const float* node = (const float*)d_in[0];
  const float* adj  = (const float*)d_in[1];
  const float* W    = (const float*)d_in[2];
  const float* sa   = (const float*)d_in[3];
  float* out = (float*)d_out;
  char* ws = (char*)d_ws;
  if (ws_size < (size_t)WS_END) return;

  float* hidden = (float*)(ws + WS_HID);
  float* f2     = (float*)(ws + WS_F2);
  float* mx     = (float*)(ws + WS_MX);
  f16*   A16    = (f16*)(ws + WS_A16);
  f16*   MT     = (f16*)(ws + WS_MT);
  f16*   P      = (f16*)(ws + WS_P);

  k_pre   <<<dim3(9216),      256, 0, stream>>>(node, W, sa, adj, hidden, f2, A16);
  k_max   <<<dim3(8),         256, 0, stream>>>(f2, mx);
  k_mt    <<<dim3(8, 129),    256, 0, stream>>>(hidden, f2, mx, MT);
  k_gemm  <<<dim3(256),       512, 0, stream>>>(A16, MT, P);
  k_div   <<<dim3(8192),      256, 0, stream>>>(P, out);
}